// Round 9
// baseline (135.928 us; speedup 1.0000x reference)
//
#include <hip/hip_runtime.h>
#include <math.h>

namespace {
constexpr int kB = 4;
constexpr int kL = 4096;
constexpr int kH = 16;
constexpr int kD = 64;
constexpr int kC = kH * kD;       // 1024 channels
constexpr int kM = 4096;          // complex FFT length (rfft of 8192 via packing)
constexpr int kN2 = kL / 2;       // 2048 packed complex samples per row
constexpr int NTH = 256;

// ---------------- scalar complex helpers (aux kernels) ----------------
__device__ __forceinline__ float2 cmul(float2 a, float2 b) {
  return make_float2(a.x * b.x - a.y * b.y, a.x * b.y + a.y * b.x);
}
__device__ __forceinline__ float2 cadd(float2 a, float2 b) { return make_float2(a.x + b.x, a.y + b.y); }
__device__ __forceinline__ float2 csub(float2 a, float2 b) { return make_float2(a.x - b.x, a.y - b.y); }
__device__ __forceinline__ float2 cconj(float2 a) { return make_float2(a.x, -a.y); }
__device__ __forceinline__ float2 cmuli(float2 a) { return make_float2(-a.y, a.x); }  // i*a
__device__ __forceinline__ float2 cscale(float2 a, float s) { return make_float2(a.x * s, a.y * s); }

// ---------------- packed-FP32 complex helpers (fft_rows) ----------------
typedef float cplx __attribute__((ext_vector_type(2)));
typedef float cplx2 __attribute__((ext_vector_type(4)));

__device__ __forceinline__ cplx pk_add(cplx a, cplx b) {
  cplx r;
  asm("v_pk_add_f32 %0, %1, %2" : "=v"(r) : "v"(a), "v"(b));
  return r;
}
__device__ __forceinline__ cplx pk_sub(cplx a, cplx b) {
  cplx r;
  asm("v_pk_add_f32 %0, %1, %2 neg_lo:[0,1] neg_hi:[0,1]" : "=v"(r) : "v"(a), "v"(b));
  return r;
}
// a + i*b = (a.x - b.y, a.y + b.x)
__device__ __forceinline__ cplx pk_addpi(cplx a, cplx b) {
  cplx r;
  asm("v_pk_add_f32 %0, %1, %2 op_sel:[0,1] op_sel_hi:[1,0] neg_lo:[0,1]" : "=v"(r) : "v"(a), "v"(b));
  return r;
}
// a - i*b = (a.x + b.y, a.y - b.x)
__device__ __forceinline__ cplx pk_addmi(cplx a, cplx b) {
  cplx r;
  asm("v_pk_add_f32 %0, %1, %2 op_sel:[0,1] op_sel_hi:[1,0] neg_hi:[0,1]" : "=v"(r) : "v"(a), "v"(b));
  return r;
}
// complex multiply: 2 VOP3P ops
__device__ __forceinline__ cplx pk_cmul(cplx a, cplx b) {
  cplx t, r;
  asm("v_pk_mul_f32 %0, %1, %2 op_sel:[0,0] op_sel_hi:[0,1]" : "=v"(t) : "v"(a), "v"(b));
  asm("v_pk_fma_f32 %0, %1, %2, %3 op_sel:[1,1,0] op_sel_hi:[1,0,1] neg_lo:[0,1,0]"
      : "=v"(r) : "v"(a), "v"(b), "v"(t));
  return r;
}

// bf16x2 pack (RNE) / unpack
__device__ __forceinline__ unsigned pkbf(float lo, float hi) {
  unsigned r;
  asm("v_cvt_pk_bf16_f32 %0, %1, %2" : "=v"(r) : "v"(lo), "v"(hi));
  return r;
}
__device__ __forceinline__ cplx unpk(unsigned d) {
  cplx r;
  r.x = __uint_as_float(d << 16);
  r.y = __uint_as_float(d & 0xffff0000u);
  return r;
}

// base-4 digit reversal of a 12-bit index (fallback kernel only)
__device__ __forceinline__ unsigned dr4(unsigned p) {
  unsigned r = __brev(p) >> 20;
  return ((r & 0x555u) << 1) | ((r >> 1) & 0x555u);
}
// base-16 digit reversal of a 12-bit index (involution)
__device__ __forceinline__ unsigned dr16(unsigned p) {
  return ((p & 15u) << 8) | (p & 0xF0u) | (p >> 8);
}
// after in-register DFT16, X[k] lives at register slot POS(k)
#define POS(k) ((((k) & 3) << 2) | ((k) >> 2))

// fallback-kernel padding
__device__ __forceinline__ int IDX(int i) { return i + (i >> 4); }
constexpr int kZPad = kM + (kM >> 4);

// depth-4 twiddle power tree: W1..W15 = w^1..w^15
#define TW_TREE(w)                                                            \
  cplx W1 = (w), W2 = pk_cmul(W1, W1), W4 = pk_cmul(W2, W2),                  \
       W8 = pk_cmul(W4, W4);                                                  \
  cplx W3 = pk_cmul(W2, W1), W5 = pk_cmul(W4, W1), W6 = pk_cmul(W4, W2),      \
       W7 = pk_cmul(W4, W3);                                                  \
  cplx W9 = pk_cmul(W8, W1), W10 = pk_cmul(W8, W2), W11 = pk_cmul(W8, W3),    \
       W12 = pk_cmul(W8, W4);                                                 \
  cplx W13 = pk_cmul(W8, W5), W14 = pk_cmul(W8, W6), W15 = pk_cmul(W8, W7);

#define TW_APPLY(r)                                                           \
  r[POS(1)] = pk_cmul(r[POS(1)], W1);   r[POS(2)] = pk_cmul(r[POS(2)], W2);   \
  r[POS(3)] = pk_cmul(r[POS(3)], W3);   r[POS(4)] = pk_cmul(r[POS(4)], W4);   \
  r[POS(5)] = pk_cmul(r[POS(5)], W5);   r[POS(6)] = pk_cmul(r[POS(6)], W6);   \
  r[POS(7)] = pk_cmul(r[POS(7)], W7);   r[POS(8)] = pk_cmul(r[POS(8)], W8);   \
  r[POS(9)] = pk_cmul(r[POS(9)], W9);   r[POS(10)] = pk_cmul(r[POS(10)], W10);\
  r[POS(11)] = pk_cmul(r[POS(11)], W11); r[POS(12)] = pk_cmul(r[POS(12)], W12);\
  r[POS(13)] = pk_cmul(r[POS(13)], W13); r[POS(14)] = pk_cmul(r[POS(14)], W14);\
  r[POS(15)] = pk_cmul(r[POS(15)], W15);

// shifted tree: B[k] = b0 * w^k, k = 0..15, depth ~4
#define TWS_TREE(b0, w)                                                       \
  cplx P2 = pk_cmul(w, w), P4 = pk_cmul(P2, P2), P8 = pk_cmul(P4, P4);        \
  cplx B0 = (b0), B1 = pk_cmul(b0, w), B2 = pk_cmul(B0, P2),                  \
       B3 = pk_cmul(B1, P2);                                                  \
  cplx B4 = pk_cmul(B0, P4), B5 = pk_cmul(B1, P4), B6 = pk_cmul(B2, P4),      \
       B7 = pk_cmul(B3, P4);                                                  \
  cplx B8 = pk_cmul(B0, P8), B9 = pk_cmul(B1, P8), B10 = pk_cmul(B2, P8),     \
       B11 = pk_cmul(B3, P8);                                                 \
  cplx B12 = pk_cmul(B4, P8), B13 = pk_cmul(B5, P8), B14 = pk_cmul(B6, P8),   \
       B15 = pk_cmul(B7, P8);

#define TWS_APPLY(r)                                                          \
  r[POS(0)] = pk_cmul(r[POS(0)], B0);   r[POS(1)] = pk_cmul(r[POS(1)], B1);   \
  r[POS(2)] = pk_cmul(r[POS(2)], B2);   r[POS(3)] = pk_cmul(r[POS(3)], B3);   \
  r[POS(4)] = pk_cmul(r[POS(4)], B4);   r[POS(5)] = pk_cmul(r[POS(5)], B5);   \
  r[POS(6)] = pk_cmul(r[POS(6)], B6);   r[POS(7)] = pk_cmul(r[POS(7)], B7);   \
  r[POS(8)] = pk_cmul(r[POS(8)], B8);   r[POS(9)] = pk_cmul(r[POS(9)], B9);   \
  r[POS(10)] = pk_cmul(r[POS(10)], B10); r[POS(11)] = pk_cmul(r[POS(11)], B11);\
  r[POS(12)] = pk_cmul(r[POS(12)], B12); r[POS(13)] = pk_cmul(r[POS(13)], B13);\
  r[POS(14)] = pk_cmul(r[POS(14)], B14); r[POS(15)] = pk_cmul(r[POS(15)], B15);

// filt[k] = amp * (1 + i k)^(-dec), with 1/M ifft scale folded into ampS
__device__ __forceinline__ float2 filt_val(float k, float ampS, float dec) {
  float mag = ampS * __expf(-0.5f * dec * log1pf(k * k));
  float ph = -dec * atanf(k);
  float s, c;
  __sincosf(ph, &s, &c);
  return make_float2(mag * c, mag * s);
}

// ---- fully-unrolled 16-point DFT in registers (packed-FP32) ----
template <int S, bool HZ>
__device__ __forceinline__ void fft16(cplx r[16]) {
  constexpr float C1 = 0.92387953251128674f;
  constexpr float S1 = 0.38268343236508978f;
  constexpr float R2 = 0.70710678118654752f;
  const float sg = (float)S;
  const cplx Wa = {C1, sg * S1};
  const cplx Wb = {R2, sg * R2};
  const cplx Wc = {S1, sg * C1};
  const cplx Wd = {-R2, sg * R2};
  const cplx We = {-C1, -sg * S1};
#pragma unroll
  for (int n2 = 0; n2 < 4; ++n2) {
    cplx t0, t1, t2, t3;
    if (HZ) {
      t0 = r[n2]; t1 = r[n2]; t2 = r[n2 + 4]; t3 = r[n2 + 4];
    } else {
      cplx a0 = r[n2], a1 = r[n2 + 4], a2 = r[n2 + 8], a3 = r[n2 + 12];
      t0 = pk_add(a0, a2); t1 = pk_sub(a0, a2); t2 = pk_add(a1, a3); t3 = pk_sub(a1, a3);
    }
    cplx u0 = pk_add(t0, t2);
    cplx u2 = pk_sub(t0, t2);
    cplx u1 = (S < 0) ? pk_addmi(t1, t3) : pk_addpi(t1, t3);
    cplx u3 = (S < 0) ? pk_addpi(t1, t3) : pk_addmi(t1, t3);
    if (n2 == 0) { r[0] = u0; r[4] = u1; r[8] = u2; r[12] = u3; }
    if (n2 == 1) { r[1] = u0; r[5] = pk_cmul(u1, Wa); r[9] = pk_cmul(u2, Wb); r[13] = pk_cmul(u3, Wc); }
    if (n2 == 2) {
      r[2] = u0; r[6] = pk_cmul(u1, Wb);
      cplx m;
      if (S < 0) { m.x = u2.y; m.y = -u2.x; } else { m.x = -u2.y; m.y = u2.x; }
      r[10] = m;
      r[14] = pk_cmul(u3, Wd);
    }
    if (n2 == 3) { r[3] = u0; r[7] = pk_cmul(u1, Wc); r[11] = pk_cmul(u2, Wd); r[15] = pk_cmul(u3, We); }
  }
#pragma unroll
  for (int s = 0; s < 4; ++s) {
    cplx b0 = r[4 * s], b1 = r[4 * s + 1], b2 = r[4 * s + 2], b3 = r[4 * s + 3];
    cplx t0 = pk_add(b0, b2), t1 = pk_sub(b0, b2), t2 = pk_add(b1, b3), t3 = pk_sub(b1, b3);
    r[4 * s] = pk_add(t0, t2);
    r[4 * s + 2] = pk_sub(t0, t2);
    r[4 * s + 1] = (S < 0) ? pk_addmi(t1, t3) : pk_addpi(t1, t3);
    r[4 * s + 3] = (S < 0) ? pk_addpi(t1, t3) : pk_addmi(t1, t3);
  }
}

// pointwise pair map (verified algebra, valid for any k in 1..4095), build_table only
__device__ __forceinline__ void pw_pair(float2 Zk, float2 Zmk, int k, float ampS, float dec,
                                        float2* Wk, float2* Wmk) {
  float2 A = cscale(cadd(Zk, cconj(Zmk)), 0.5f);
  float2 Bv = cscale(csub(Zk, cconj(Zmk)), 0.5f);
  float sn, cs;
  __sincosf(-3.14159265358979323846f * (float)k / (float)kM, &sn, &cs);
  float2 tw = make_float2(cs, sn);
  float2 P = cmuli(cmul(tw, Bv));
  float2 Xk = csub(A, P);
  float2 Xmk = cconj(cadd(A, P));
  float2 Yk = cmul(Xk, filt_val((float)k, ampS, dec));
  float2 Ymk = cmul(Xmk, filt_val((float)(kM - k), ampS, dec));
  float2 Ev = cscale(cadd(Yk, cconj(Ymk)), 0.5f);
  float2 Ov = cscale(cmul(cconj(tw), csub(Yk, cconj(Ymk))), 0.5f);
  float2 iO = cmuli(Ov);
  *Wk = cadd(Ev, iO);
  *Wmk = cconj(csub(Ev, iO));
}
}  // namespace

// ---------- pass 0: position-keyed (alpha,beta) table: W[p] = a*Z[p] + b*conj(Z[p2]) ----------
// keyed [h][j2][t]: thread t=(k1,j1), element j2 -> position p = k1*256 + j1*16 + j2
__global__ __launch_bounds__(256) void build_table(const float* __restrict__ la,
                                                   const float* __restrict__ ld,
                                                   float4* __restrict__ tab) {
  const int j2 = blockIdx.x;  // 0..15
  const int h = blockIdx.y;
  const int t = threadIdx.x;  // 0..255
  const int k1 = t >> 4, j1 = t & 15;
  float av = la[h], dv = ld[h];
  float amp = (av > 20.f) ? av : log1pf(__expf(av));
  float dec = ((dv > 20.f) ? dv : log1pf(__expf(dv))) + 1e-4f;
  float ampS = amp * (1.0f / (float)kM);
  int p = (k1 << 8) + (j1 << 4) + j2;
  float2 al, be;
  if (p == 0) {
    float F0 = filt_val(0.f, ampS, dec).x;
    float FM = filt_val((float)kM, ampS, dec).x;
    al = make_float2(0.5f * (F0 + FM), 0.f);
    be = make_float2(0.f, 0.5f * (F0 - FM));
  } else if (p == 8) {
    al = cconj(filt_val((float)(kM / 2), ampS, dec));  // bin 2048: W = conj(filt)*Z
    be = make_float2(0.f, 0.f);
  } else {
    int k = (int)dr16((unsigned)p);
    float2 a, b, g, d;
    pw_pair(make_float2(1.f, 0.f), make_float2(0.f, 0.f), k, ampS, dec, &a, &g);
    pw_pair(make_float2(0.f, 0.f), make_float2(1.f, 0.f), k, ampS, dec, &b, &d);
    al = a; be = b;
  }
  tab[(((size_t)h * 16 + j2) << 8) + t] = make_float4(al.x, al.y, be.x, be.y);
}

// ---------- pass 1: transpose + pack x (B,L,C) -> z bf16x2 (B,C,L/2) ----------
__global__ __launch_bounds__(256) void transpose_fwd(const float* __restrict__ in,
                                                     unsigned* __restrict__ zout) {
  __shared__ float T[64][33];
  const int b = blockIdx.z;
  const int l0 = blockIdx.x * 64;
  const int c0 = blockIdx.y * 32;
  const float* ib = in + (size_t)b * kL * kC;
  unsigned* ob = zout + (size_t)b * kC * kN2;
  const int tx = threadIdx.x & 31, ty = threadIdx.x >> 5;
#pragma unroll
  for (int i = 0; i < 64; i += 8)
    T[ty + i][tx] = ib[(size_t)(l0 + ty + i) * kC + c0 + tx];
  __syncthreads();
  const int n0 = l0 >> 1;
#pragma unroll
  for (int i = 0; i < 32; i += 8) {
    int c = ty + i;
    ob[(size_t)(c0 + c) * kN2 + n0 + tx] = pkbf(T[2 * tx][c], T[2 * tx + 1][c]);
  }
}

// ---------- pass 2: per-row FFT conv; pair-XOR swizzle phys(p) = p ^ ((p>>4)&14) ----------
__global__ __launch_bounds__(NTH) void fft_rows(unsigned* __restrict__ zio,
                                                const float4* __restrict__ tab) {
  __shared__ __align__(16) cplx Z[kM];  // 32 KB
  const int row = blockIdx.x;  // b*1024 + c
  const int h = (row >> 6) & (kH - 1);
  const int t = threadIdx.x;
  unsigned* zrow = zio + (size_t)row * kN2;

  cplx r[16];
  const int swt = t ^ ((t >> 4) & 14);

  // ---- F1: global load (bf16x2), DFT16 over n1, twiddle W4096^{t*k1} ----
  {
    unsigned din[8];
#pragma unroll
    for (int j = 0; j < 8; ++j) din[j] = zrow[t + (j << 8)];
#pragma unroll
    for (int j = 0; j < 8; ++j) r[j] = unpk(din[j]);
    fft16<-1, true>(r);
    float sn, cs;
    __sincosf(-6.283185307179586f * (float)t / 4096.f, &sn, &cs);
    cplx w = {cs, sn};
    TW_TREE(w);
    TW_APPLY(r);
    cplx* Zb = &Z[swt];
#pragma unroll
    for (int k1 = 0; k1 < 16; ++k1) Zb[k1 << 8] = r[POS(k1)];
  }
  __syncthreads();

  // ---- F2: DFT16 over m1 (stride 16), twiddle W256^{m2*j1} ----
  {
    const int g = t >> 4, m2 = t & 15;
    const int base = g << 8;
#pragma unroll
    for (int m1 = 0; m1 < 16; ++m1) r[m1] = Z[base + (m1 << 4) + (m2 ^ (m1 & 14))];
    fft16<-1, false>(r);
    float sn, cs;
    __sincosf(-6.283185307179586f * (float)m2 / 256.f, &sn, &cs);
    cplx w = {cs, sn};
    TW_TREE(w);
    TW_APPLY(r);
#pragma unroll
    for (int j1 = 0; j1 < 16; ++j1) Z[base + (j1 << 4) + (m2 ^ (j1 & 14))] = r[POS(j1)];
  }
  __syncthreads();

  // ---- F3 + pointwise + I1 fused on run (k1,j1) ----
  {
    const int k1 = t >> 4, j1 = t & 15;
    const int base = (k1 << 8) + (j1 << 4);
    const int xo = j1 & 14;
    cplx2* Zp = (cplx2*)Z;

    // F3: read own run (b128 pairs), DFT16 over m2, publish for partner
#pragma unroll
    for (int q = 0; q < 8; ++q) {
      cplx2 v = Zp[(base + ((2 * q) ^ xo)) >> 1];
      r[2 * q].x = v.x; r[2 * q].y = v.y;
      r[2 * q + 1].x = v.z; r[2 * q + 1].y = v.w;
    }
    fft16<-1, false>(r);
#pragma unroll
    for (int q = 0; q < 8; ++q) {
      cplx a = r[POS(2 * q)], b = r[POS(2 * q + 1)];
      cplx2 v; v.x = a.x; v.y = a.y; v.z = b.x; v.w = b.y;
      Zp[(base + ((2 * q) ^ xo)) >> 1] = v;
    }
    __syncthreads();

    // partner run: base2 & pair-XOR of partner's j1-digit
    const int base2 = (k1 == 0) ? (((16 - j1) & 15) << 4)
                                : (((16 - k1) << 8) + ((15 - j1) << 4));
    const int xo2 = ((k1 == 0) ? ((16 - j1) & 15) : (15 - j1)) & 14;
    cplx P[16];
#pragma unroll
    for (int q = 0; q < 8; ++q) {
      cplx2 v = Zp[(base2 + ((2 * q) ^ xo2)) >> 1];
      P[2 * q].x = v.x; P[2 * q].y = v.y;
      P[2 * q + 1].x = v.z; P[2 * q + 1].y = v.w;
    }
    // W[j2] = alpha*own[j2] + beta*conj(P[idx]); own[j2] = r[POS(j2)]
    const float4* tb = tab + ((size_t)h << 12) + t;
    cplx Wv[16];
    const bool sp = (t == 0);  // thread (0,0): partner order (16-j2)&15
#pragma unroll
    for (int j2 = 0; j2 < 16; ++j2) {
      float4 cc = tb[j2 << 8];
      cplx a_; a_.x = cc.x; a_.y = cc.y;
      cplx b_; b_.x = cc.z; b_.y = cc.w;
      cplx zm = sp ? P[(16 - j2) & 15] : P[15 - j2];
      cplx zmc; zmc.x = zm.x; zmc.y = -zm.y;
      Wv[j2] = pk_add(pk_cmul(a_, r[POS(j2)]), pk_cmul(b_, zmc));
    }
    __syncthreads();  // all partner reads complete before I1 writes

    // I1: IDFT16 over j2, twiddle e^{+2pi i j1*m2/256}, write own run
    fft16<1, false>(Wv);
    float sn, cs;
    __sincosf(6.283185307179586f * (float)j1 / 256.f, &sn, &cs);
    cplx w = {cs, sn};
    TW_TREE(w);
    TW_APPLY(Wv);
#pragma unroll
    for (int q = 0; q < 8; ++q) {
      cplx a = Wv[POS(2 * q)], b = Wv[POS(2 * q + 1)];
      cplx2 v; v.x = a.x; v.y = a.y; v.z = b.x; v.w = b.y;
      Zp[(base + ((2 * q) ^ xo)) >> 1] = v;
    }
  }
  __syncthreads();

  // ---- I2: IDFT16 over j1 (stride 16), twiddle e^{+2pi i k1*(m1*16+m2)/4096} ----
  {
    const int k1 = t >> 4, m2 = t & 15;
#pragma unroll
    for (int j1 = 0; j1 < 16; ++j1) r[j1] = Z[(k1 << 8) + (j1 << 4) + (m2 ^ (j1 & 14))];
    fft16<1, false>(r);
    float sn, cs;
    __sincosf(6.283185307179586f * (float)(k1 * m2) / 4096.f, &sn, &cs);
    cplx b0 = {cs, sn};
    __sincosf(6.283185307179586f * (float)k1 / 256.f, &sn, &cs);
    cplx w = {cs, sn};
    TWS_TREE(b0, w);
    TWS_APPLY(r);
#pragma unroll
    for (int m1 = 0; m1 < 16; ++m1) Z[(k1 << 8) + (m1 << 4) + (m2 ^ (m1 & 14))] = r[POS(m1)];
  }
  __syncthreads();

  // ---- I3: IDFT16 over k1 (stride 256), bf16x2 coalesced global store ----
  {
    cplx* Zb = &Z[swt];
#pragma unroll
    for (int k1 = 0; k1 < 16; ++k1) r[k1] = Zb[k1 << 8];
    fft16<1, false>(r);
#pragma unroll
    for (int n1 = 0; n1 < 8; ++n1) {
      cplx v = r[POS(n1)];
      zrow[(n1 << 8) + t] = pkbf(v.x, v.y);
    }
  }
}

// ---------- pass 3: transpose back z (B,C,L/2) -> out (B,L,C) + mix ----------
__global__ __launch_bounds__(256) void mix_out(const unsigned* __restrict__ zin,
                                               const float* __restrict__ x,
                                               const float* __restrict__ mix_logit,
                                               float* __restrict__ outp) {
  __shared__ float T[64][33];
  const int b = blockIdx.z;
  const int l0 = blockIdx.x * 64;
  const int c0 = blockIdx.y * 32;
  const int h = c0 >> 6;
  const float ml = mix_logit[h];
  const float mix = 1.0f / (1.0f + __expf(-ml));
  const float omix = 1.0f - mix;
  const unsigned* yb = zin + (size_t)b * kC * kN2;
  const float* xb = x + (size_t)b * kL * kC;
  float* ob = outp + (size_t)b * kL * kC;
  const int tx = threadIdx.x & 31, ty = threadIdx.x >> 5;
  const int n0 = l0 >> 1;
#pragma unroll
  for (int i = 0; i < 32; i += 8) {
    int c = ty + i;
    unsigned d = yb[(size_t)(c0 + c) * kN2 + n0 + tx];
    T[2 * tx][c] = __uint_as_float(d << 16);
    T[2 * tx + 1][c] = __uint_as_float(d & 0xffff0000u);
  }
  __syncthreads();
#pragma unroll
  for (int i = 0; i < 64; i += 8) {
    int l = ty + i;
    size_t idx = (size_t)(l0 + l) * kC + c0 + tx;
    ob[idx] = mix * T[l][tx] + omix * xb[idx];
  }
}

// ---------- fallback (round-1 single kernel) if ws is too small ----------
__global__ __launch_bounds__(NTH) void fftconv_fallback(
    const float* __restrict__ x, const float* __restrict__ log_amp,
    const float* __restrict__ log_decay, const float* __restrict__ mix_logit,
    float* __restrict__ out) {
  __shared__ float2 Z[kZPad];
  const int row = blockIdx.x;
  const int d = row & (kD - 1);
  const int h = (row >> 6) & (kH - 1);
  const int b = row >> 10;
  const int t = threadIdx.x;
  const size_t rowoff = (size_t)b * kL * kC + (size_t)h * kD + (size_t)d;
  const float* xrow = x + rowoff;
  float* orow = out + rowoff;

  const float av = log_amp[h];
  const float dv = log_decay[h];
  const float amp = (av > 20.f) ? av : log1pf(__expf(av));
  const float dec = ((dv > 20.f) ? dv : log1pf(__expf(dv))) + 1e-4f;
  const float ampS = amp * (1.0f / (float)kM);
  const float ml = mix_logit[h];
  const float mix = 1.0f / (1.0f + __expf(-ml));
  const float omix = 1.0f - mix;

  for (int i = 0; i < kM / NTH; ++i) {
    int n = t + i * NTH;
    float2 z;
    if (n < kL / 2) {
      z.x = xrow[(size_t)(2 * n) * kC];
      z.y = xrow[(size_t)(2 * n + 1) * kC];
    } else {
      z = make_float2(0.f, 0.f);
    }
    Z[IDX(n)] = z;
  }
  __syncthreads();

  for (int Ls = kM; Ls >= 4; Ls >>= 2) {
    const int q = Ls >> 2;
    const float wstep = -6.283185307179586f / (float)Ls;
    for (int i = 0; i < kM / 4 / NTH; ++i) {
      int bt = t + i * NTH;
      int jj = bt & (q - 1);
      int base = ((bt - jj) << 2) + jj;
      float2 a = Z[IDX(base)], bb = Z[IDX(base + q)];
      float2 c = Z[IDX(base + 2 * q)], dd = Z[IDX(base + 3 * q)];
      float2 t0 = cadd(a, c), t1 = csub(a, c), t2 = cadd(bb, dd), t3 = csub(bb, dd);
      float2 u0 = cadd(t0, t2), u2 = csub(t0, t2);
      float2 it3 = cmuli(t3);
      float2 u1 = csub(t1, it3), u3 = cadd(t1, it3);
      float sn, cs;
      __sincosf(wstep * (float)jj, &sn, &cs);
      float2 w1 = make_float2(cs, sn);
      float2 w2 = cmul(w1, w1);
      float2 w3 = cmul(w2, w1);
      Z[IDX(base)] = u0;
      Z[IDX(base + q)] = cmul(u1, w1);
      Z[IDX(base + 2 * q)] = cmul(u2, w2);
      Z[IDX(base + 3 * q)] = cmul(u3, w3);
    }
    __syncthreads();
  }

  for (int i = 0; i <= kM / 2 / NTH; ++i) {
    int k = t + i * NTH;
    if (k > kM / 2) continue;
    if (k == 0) {
      float2 Z0 = Z[IDX(0)];
      float X0 = Z0.x + Z0.y;
      float XM = Z0.x - Z0.y;
      float2 f0 = filt_val(0.f, ampS, dec);
      float2 fM = filt_val((float)kM, ampS, dec);
      float Y0 = X0 * f0.x;
      float YM = XM * fM.x;
      Z[IDX(0)] = make_float2(0.5f * (Y0 + YM), 0.5f * (Y0 - YM));
    } else if (k == kM / 2) {
      unsigned p = dr4(kM / 2);
      float2 Zk = Z[IDX(p)];
      float2 f = filt_val((float)(kM / 2), ampS, dec);
      float2 Y = cmul(cconj(Zk), f);
      Z[IDX(p)] = cconj(Y);
    } else {
      unsigned pk = dr4((unsigned)k), pmk = dr4((unsigned)(kM - k));
      float2 Zk = Z[IDX(pk)], Zmk = Z[IDX(pmk)];
      float2 A = cscale(cadd(Zk, cconj(Zmk)), 0.5f);
      float2 Bv = cscale(csub(Zk, cconj(Zmk)), 0.5f);
      float sn, cs;
      __sincosf(-3.14159265358979323846f * (float)k / (float)kM, &sn, &cs);
      float2 tw = make_float2(cs, sn);
      float2 P = cmuli(cmul(tw, Bv));
      float2 Xk = csub(A, P);
      float2 Xmk = cconj(cadd(A, P));
      float2 Yk = cmul(Xk, filt_val((float)k, ampS, dec));
      float2 Ymk = cmul(Xmk, filt_val((float)(kM - k), ampS, dec));
      float2 Ev = cscale(cadd(Yk, cconj(Ymk)), 0.5f);
      float2 Ov = cscale(cmul(cconj(tw), csub(Yk, cconj(Ymk))), 0.5f);
      float2 iO = cmuli(Ov);
      Z[IDX(pk)] = cadd(Ev, iO);
      Z[IDX(pmk)] = cconj(csub(Ev, iO));
    }
  }
  __syncthreads();

  for (int Ls = 4; Ls <= kM; Ls <<= 2) {
    const int q = Ls >> 2;
    const float wstep = 6.283185307179586f / (float)Ls;
    for (int i = 0; i < kM / 4 / NTH; ++i) {
      int bt = t + i * NTH;
      int jj = bt & (q - 1);
      int base = ((bt - jj) << 2) + jj;
      float sn, cs;
      __sincosf(wstep * (float)jj, &sn, &cs);
      float2 w1 = make_float2(cs, sn);
      float2 w2 = cmul(w1, w1);
      float2 w3 = cmul(w2, w1);
      float2 a = Z[IDX(base)];
      float2 bb = cmul(Z[IDX(base + q)], w1);
      float2 c = cmul(Z[IDX(base + 2 * q)], w2);
      float2 dd = cmul(Z[IDX(base + 3 * q)], w3);
      float2 s0 = cadd(a, c), s1 = csub(a, c), s2 = cadd(bb, dd), s3 = csub(bb, dd);
      float2 is3 = cmuli(s3);
      Z[IDX(base)] = cadd(s0, s2);
      Z[IDX(base + 2 * q)] = csub(s0, s2);
      Z[IDX(base + q)] = cadd(s1, is3);
      Z[IDX(base + 3 * q)] = csub(s1, is3);
    }
    __syncthreads();
  }

  for (int i = 0; i < kL / 2 / NTH; ++i) {
    int n = t + i * NTH;
    float2 w = Z[IDX(n)];
    size_t i0 = (size_t)(2 * n) * kC;
    float x0 = xrow[i0];
    float x1 = xrow[i0 + kC];
    orow[i0] = mix * w.x + omix * x0;
    orow[i0 + kC] = mix * w.y + omix * x1;
  }
}

extern "C" void kernel_launch(void* const* d_in, const int* in_sizes, int n_in,
                              void* d_out, int out_size, void* d_ws, size_t ws_size,
                              hipStream_t stream) {
  const float* x = (const float*)d_in[0];
  const float* la = (const float*)d_in[1];
  const float* ld = (const float*)d_in[2];
  const float* ml = (const float*)d_in[3];
  float* out = (float*)d_out;
  const size_t zbytes = (size_t)kB * kC * kN2 * sizeof(unsigned);        // 32 MiB
  const size_t tabbytes = (size_t)kH * 16 * 256 * sizeof(float4);        // 1 MiB
  if (ws_size >= zbytes + tabbytes) {
    unsigned* wsz = (unsigned*)d_ws;
    float4* tab = (float4*)((char*)d_ws + zbytes);
    build_table<<<dim3(16, kH), dim3(256), 0, stream>>>(la, ld, tab);
    transpose_fwd<<<dim3(kL / 64, kC / 32, kB), dim3(256), 0, stream>>>(x, wsz);
    fft_rows<<<dim3(kB * kC), dim3(NTH), 0, stream>>>(wsz, tab);
    mix_out<<<dim3(kL / 64, kC / 32, kB), dim3(256), 0, stream>>>(wsz, x, ml, out);
  } else {
    fftconv_fallback<<<dim3(kB * kC), dim3(NTH), 0, stream>>>(x, la, ld, ml, out);
  }
}

// Round 10
// 98.155 us; speedup vs baseline: 1.3848x; 1.3848x over previous
//
#include <hip/hip_runtime.h>
#include <math.h>

namespace {
constexpr int kB = 4;
constexpr int kL = 4096;
constexpr int kH = 16;
constexpr int kD = 64;
constexpr int kC = kH * kD;       // 1024 channels
constexpr int kM = 4096;          // complex FFT length (rfft of 8192 via packing)
constexpr int kN2 = kL / 2;       // 2048 packed complex samples per row
constexpr int NTH = 256;

// ---------------- scalar complex helpers (aux kernels) ----------------
__device__ __forceinline__ float2 cmul(float2 a, float2 b) {
  return make_float2(a.x * b.x - a.y * b.y, a.x * b.y + a.y * b.x);
}
__device__ __forceinline__ float2 cadd(float2 a, float2 b) { return make_float2(a.x + b.x, a.y + b.y); }
__device__ __forceinline__ float2 csub(float2 a, float2 b) { return make_float2(a.x - b.x, a.y - b.y); }
__device__ __forceinline__ float2 cconj(float2 a) { return make_float2(a.x, -a.y); }
__device__ __forceinline__ float2 cmuli(float2 a) { return make_float2(-a.y, a.x); }  // i*a
__device__ __forceinline__ float2 cscale(float2 a, float s) { return make_float2(a.x * s, a.y * s); }

// ---------------- packed-FP32 complex helpers (fft_rows) ----------------
typedef float cplx __attribute__((ext_vector_type(2)));

__device__ __forceinline__ cplx pk_add(cplx a, cplx b) {
  cplx r;
  asm("v_pk_add_f32 %0, %1, %2" : "=v"(r) : "v"(a), "v"(b));
  return r;
}
__device__ __forceinline__ cplx pk_sub(cplx a, cplx b) {
  cplx r;
  asm("v_pk_add_f32 %0, %1, %2 neg_lo:[0,1] neg_hi:[0,1]" : "=v"(r) : "v"(a), "v"(b));
  return r;
}
// a + i*b = (a.x - b.y, a.y + b.x)
__device__ __forceinline__ cplx pk_addpi(cplx a, cplx b) {
  cplx r;
  asm("v_pk_add_f32 %0, %1, %2 op_sel:[0,1] op_sel_hi:[1,0] neg_lo:[0,1]" : "=v"(r) : "v"(a), "v"(b));
  return r;
}
// a - i*b = (a.x + b.y, a.y - b.x)
__device__ __forceinline__ cplx pk_addmi(cplx a, cplx b) {
  cplx r;
  asm("v_pk_add_f32 %0, %1, %2 op_sel:[0,1] op_sel_hi:[1,0] neg_hi:[0,1]" : "=v"(r) : "v"(a), "v"(b));
  return r;
}
// complex multiply: 2 VOP3P ops
__device__ __forceinline__ cplx pk_cmul(cplx a, cplx b) {
  cplx t, r;
  asm("v_pk_mul_f32 %0, %1, %2 op_sel:[0,0] op_sel_hi:[0,1]" : "=v"(t) : "v"(a), "v"(b));
  asm("v_pk_fma_f32 %0, %1, %2, %3 op_sel:[1,1,0] op_sel_hi:[1,0,1] neg_lo:[0,1,0]"
      : "=v"(r) : "v"(a), "v"(b), "v"(t));
  return r;
}

// bf16x2 pack (RNE) / unpack
__device__ __forceinline__ unsigned pkbf(float lo, float hi) {
  unsigned r;
  asm("v_cvt_pk_bf16_f32 %0, %1, %2" : "=v"(r) : "v"(lo), "v"(hi));
  return r;
}
__device__ __forceinline__ cplx unpk(unsigned d) {
  cplx r;
  r.x = __uint_as_float(d << 16);
  r.y = __uint_as_float(d & 0xffff0000u);
  return r;
}

// base-4 digit reversal of a 12-bit index (fallback kernel only)
__device__ __forceinline__ unsigned dr4(unsigned p) {
  unsigned r = __brev(p) >> 20;
  return ((r & 0x555u) << 1) | ((r >> 1) & 0x555u);
}
// base-16 digit reversal of a 12-bit index (involution)
__device__ __forceinline__ unsigned dr16(unsigned p) {
  return ((p & 15u) << 8) | (p & 0xF0u) | (p >> 8);
}
// after in-register DFT16, X[k] lives at register slot POS(k)
#define POS(k) ((((k) & 3) << 2) | ((k) >> 2))

// fallback-kernel padding
__device__ __forceinline__ int IDX(int i) { return i + (i >> 4); }
constexpr int kZPad = kM + (kM >> 4);

// depth-4 twiddle power tree: W1..W15 = w^1..w^15
#define TW_TREE(w)                                                            \
  cplx W1 = (w), W2 = pk_cmul(W1, W1), W4 = pk_cmul(W2, W2),                  \
       W8 = pk_cmul(W4, W4);                                                  \
  cplx W3 = pk_cmul(W2, W1), W5 = pk_cmul(W4, W1), W6 = pk_cmul(W4, W2),      \
       W7 = pk_cmul(W4, W3);                                                  \
  cplx W9 = pk_cmul(W8, W1), W10 = pk_cmul(W8, W2), W11 = pk_cmul(W8, W3),    \
       W12 = pk_cmul(W8, W4);                                                 \
  cplx W13 = pk_cmul(W8, W5), W14 = pk_cmul(W8, W6), W15 = pk_cmul(W8, W7);

#define TW_APPLY(r)                                                           \
  r[POS(1)] = pk_cmul(r[POS(1)], W1);   r[POS(2)] = pk_cmul(r[POS(2)], W2);   \
  r[POS(3)] = pk_cmul(r[POS(3)], W3);   r[POS(4)] = pk_cmul(r[POS(4)], W4);   \
  r[POS(5)] = pk_cmul(r[POS(5)], W5);   r[POS(6)] = pk_cmul(r[POS(6)], W6);   \
  r[POS(7)] = pk_cmul(r[POS(7)], W7);   r[POS(8)] = pk_cmul(r[POS(8)], W8);   \
  r[POS(9)] = pk_cmul(r[POS(9)], W9);   r[POS(10)] = pk_cmul(r[POS(10)], W10);\
  r[POS(11)] = pk_cmul(r[POS(11)], W11); r[POS(12)] = pk_cmul(r[POS(12)], W12);\
  r[POS(13)] = pk_cmul(r[POS(13)], W13); r[POS(14)] = pk_cmul(r[POS(14)], W14);\
  r[POS(15)] = pk_cmul(r[POS(15)], W15);

// shifted tree: B[k] = b0 * w^k, k = 0..15, depth ~4
#define TWS_TREE(b0, w)                                                       \
  cplx P2 = pk_cmul(w, w), P4 = pk_cmul(P2, P2), P8 = pk_cmul(P4, P4);        \
  cplx B0 = (b0), B1 = pk_cmul(b0, w), B2 = pk_cmul(B0, P2),                  \
       B3 = pk_cmul(B1, P2);                                                  \
  cplx B4 = pk_cmul(B0, P4), B5 = pk_cmul(B1, P4), B6 = pk_cmul(B2, P4),      \
       B7 = pk_cmul(B3, P4);                                                  \
  cplx B8 = pk_cmul(B0, P8), B9 = pk_cmul(B1, P8), B10 = pk_cmul(B2, P8),     \
       B11 = pk_cmul(B3, P8);                                                 \
  cplx B12 = pk_cmul(B4, P8), B13 = pk_cmul(B5, P8), B14 = pk_cmul(B6, P8),   \
       B15 = pk_cmul(B7, P8);

#define TWS_APPLY(r)                                                          \
  r[POS(0)] = pk_cmul(r[POS(0)], B0);   r[POS(1)] = pk_cmul(r[POS(1)], B1);   \
  r[POS(2)] = pk_cmul(r[POS(2)], B2);   r[POS(3)] = pk_cmul(r[POS(3)], B3);   \
  r[POS(4)] = pk_cmul(r[POS(4)], B4);   r[POS(5)] = pk_cmul(r[POS(5)], B5);   \
  r[POS(6)] = pk_cmul(r[POS(6)], B6);   r[POS(7)] = pk_cmul(r[POS(7)], B7);   \
  r[POS(8)] = pk_cmul(r[POS(8)], B8);   r[POS(9)] = pk_cmul(r[POS(9)], B9);   \
  r[POS(10)] = pk_cmul(r[POS(10)], B10); r[POS(11)] = pk_cmul(r[POS(11)], B11);\
  r[POS(12)] = pk_cmul(r[POS(12)], B12); r[POS(13)] = pk_cmul(r[POS(13)], B13);\
  r[POS(14)] = pk_cmul(r[POS(14)], B14); r[POS(15)] = pk_cmul(r[POS(15)], B15);

// filt[k] = amp * (1 + i k)^(-dec), with 1/M ifft scale folded into ampS
__device__ __forceinline__ float2 filt_val(float k, float ampS, float dec) {
  float mag = ampS * __expf(-0.5f * dec * log1pf(k * k));
  float ph = -dec * atanf(k);
  float s, c;
  __sincosf(ph, &s, &c);
  return make_float2(mag * c, mag * s);
}

// ---- fully-unrolled 16-point DFT in registers (packed-FP32) ----
template <int S, bool HZ>
__device__ __forceinline__ void fft16(cplx r[16]) {
  constexpr float C1 = 0.92387953251128674f;
  constexpr float S1 = 0.38268343236508978f;
  constexpr float R2 = 0.70710678118654752f;
  const float sg = (float)S;
  const cplx Wa = {C1, sg * S1};
  const cplx Wb = {R2, sg * R2};
  const cplx Wc = {S1, sg * C1};
  const cplx Wd = {-R2, sg * R2};
  const cplx We = {-C1, -sg * S1};
#pragma unroll
  for (int n2 = 0; n2 < 4; ++n2) {
    cplx t0, t1, t2, t3;
    if (HZ) {
      t0 = r[n2]; t1 = r[n2]; t2 = r[n2 + 4]; t3 = r[n2 + 4];
    } else {
      cplx a0 = r[n2], a1 = r[n2 + 4], a2 = r[n2 + 8], a3 = r[n2 + 12];
      t0 = pk_add(a0, a2); t1 = pk_sub(a0, a2); t2 = pk_add(a1, a3); t3 = pk_sub(a1, a3);
    }
    cplx u0 = pk_add(t0, t2);
    cplx u2 = pk_sub(t0, t2);
    cplx u1 = (S < 0) ? pk_addmi(t1, t3) : pk_addpi(t1, t3);
    cplx u3 = (S < 0) ? pk_addpi(t1, t3) : pk_addmi(t1, t3);
    if (n2 == 0) { r[0] = u0; r[4] = u1; r[8] = u2; r[12] = u3; }
    if (n2 == 1) { r[1] = u0; r[5] = pk_cmul(u1, Wa); r[9] = pk_cmul(u2, Wb); r[13] = pk_cmul(u3, Wc); }
    if (n2 == 2) {
      r[2] = u0; r[6] = pk_cmul(u1, Wb);
      cplx m;
      if (S < 0) { m.x = u2.y; m.y = -u2.x; } else { m.x = -u2.y; m.y = u2.x; }
      r[10] = m;
      r[14] = pk_cmul(u3, Wd);
    }
    if (n2 == 3) { r[3] = u0; r[7] = pk_cmul(u1, Wc); r[11] = pk_cmul(u2, Wd); r[15] = pk_cmul(u3, We); }
  }
#pragma unroll
  for (int s = 0; s < 4; ++s) {
    cplx b0 = r[4 * s], b1 = r[4 * s + 1], b2 = r[4 * s + 2], b3 = r[4 * s + 3];
    cplx t0 = pk_add(b0, b2), t1 = pk_sub(b0, b2), t2 = pk_add(b1, b3), t3 = pk_sub(b1, b3);
    r[4 * s] = pk_add(t0, t2);
    r[4 * s + 2] = pk_sub(t0, t2);
    r[4 * s + 1] = (S < 0) ? pk_addmi(t1, t3) : pk_addpi(t1, t3);
    r[4 * s + 3] = (S < 0) ? pk_addpi(t1, t3) : pk_addmi(t1, t3);
  }
}

// pointwise pair map (verified algebra, valid for any k in 1..4095), build_table only
__device__ __forceinline__ void pw_pair(float2 Zk, float2 Zmk, int k, float ampS, float dec,
                                        float2* Wk, float2* Wmk) {
  float2 A = cscale(cadd(Zk, cconj(Zmk)), 0.5f);
  float2 Bv = cscale(csub(Zk, cconj(Zmk)), 0.5f);
  float sn, cs;
  __sincosf(-3.14159265358979323846f * (float)k / (float)kM, &sn, &cs);
  float2 tw = make_float2(cs, sn);
  float2 P = cmuli(cmul(tw, Bv));
  float2 Xk = csub(A, P);
  float2 Xmk = cconj(cadd(A, P));
  float2 Yk = cmul(Xk, filt_val((float)k, ampS, dec));
  float2 Ymk = cmul(Xmk, filt_val((float)(kM - k), ampS, dec));
  float2 Ev = cscale(cadd(Yk, cconj(Ymk)), 0.5f);
  float2 Ov = cscale(cmul(cconj(tw), csub(Yk, cconj(Ymk))), 0.5f);
  float2 iO = cmuli(Ov);
  *Wk = cadd(Ev, iO);
  *Wmk = cconj(csub(Ev, iO));
}
}  // namespace

// ---------- pass 0: position-keyed (alpha,beta) table: W[p] = a*Z[p] + b*conj(Z[p2]) ----------
// keyed [h][j2][t]: thread t=(k1,j1), element j2 -> position p = k1*256 + j1*16 + j2
// (layout + algebra verified correct in round 9)
__global__ __launch_bounds__(256) void build_table(const float* __restrict__ la,
                                                   const float* __restrict__ ld,
                                                   float4* __restrict__ tab) {
  const int j2 = blockIdx.x;  // 0..15
  const int h = blockIdx.y;
  const int t = threadIdx.x;  // 0..255
  const int k1 = t >> 4, j1 = t & 15;
  float av = la[h], dv = ld[h];
  float amp = (av > 20.f) ? av : log1pf(__expf(av));
  float dec = ((dv > 20.f) ? dv : log1pf(__expf(dv))) + 1e-4f;
  float ampS = amp * (1.0f / (float)kM);
  int p = (k1 << 8) + (j1 << 4) + j2;
  float2 al, be;
  if (p == 0) {
    float F0 = filt_val(0.f, ampS, dec).x;
    float FM = filt_val((float)kM, ampS, dec).x;
    al = make_float2(0.5f * (F0 + FM), 0.f);
    be = make_float2(0.f, 0.5f * (F0 - FM));
  } else if (p == 8) {
    al = cconj(filt_val((float)(kM / 2), ampS, dec));  // bin 2048: W = conj(filt)*Z
    be = make_float2(0.f, 0.f);
  } else {
    int k = (int)dr16((unsigned)p);
    float2 a, b, g, d;
    pw_pair(make_float2(1.f, 0.f), make_float2(0.f, 0.f), k, ampS, dec, &a, &g);
    pw_pair(make_float2(0.f, 0.f), make_float2(1.f, 0.f), k, ampS, dec, &b, &d);
    al = a; be = b;
  }
  tab[(((size_t)h * 16 + j2) << 8) + t] = make_float4(al.x, al.y, be.x, be.y);
}

// ---------- pass 1: transpose + pack x (B,L,C) -> z bf16x2 (B,C,L/2) ----------
__global__ __launch_bounds__(256) void transpose_fwd(const float* __restrict__ in,
                                                     unsigned* __restrict__ zout) {
  __shared__ float T[64][33];
  const int b = blockIdx.z;
  const int l0 = blockIdx.x * 64;
  const int c0 = blockIdx.y * 32;
  const float* ib = in + (size_t)b * kL * kC;
  unsigned* ob = zout + (size_t)b * kC * kN2;
  const int tx = threadIdx.x & 31, ty = threadIdx.x >> 5;
#pragma unroll
  for (int i = 0; i < 64; i += 8)
    T[ty + i][tx] = ib[(size_t)(l0 + ty + i) * kC + c0 + tx];
  __syncthreads();
  const int n0 = l0 >> 1;
#pragma unroll
  for (int i = 0; i < 32; i += 8) {
    int c = ty + i;
    ob[(size_t)(c0 + c) * kN2 + n0 + tx] = pkbf(T[2 * tx][c], T[2 * tx + 1][c]);
  }
}

// ---------- pass 2: per-row FFT conv (16^3 register radix-16, packed math) ----------
// XOR swizzle (round-8): position p stored at phys p ^ ((p>>4)&15)
__global__ __launch_bounds__(NTH) void fft_rows(unsigned* __restrict__ zio,
                                                const float4* __restrict__ tab) {
  __shared__ cplx Z[kM];  // 32 KB
  const int row = blockIdx.x;  // b*1024 + c
  const int h = (row >> 6) & (kH - 1);
  const int t = threadIdx.x;
  unsigned* zrow = zio + (size_t)row * kN2;

  cplx r[16];
  const int swt = t ^ ((t >> 4) & 15);

  // ---- F1: global load (bf16x2), DFT16 over n1, twiddle W4096^{t*k1} ----
  {
    unsigned din[8];
#pragma unroll
    for (int j = 0; j < 8; ++j) din[j] = zrow[t + (j << 8)];
#pragma unroll
    for (int j = 0; j < 8; ++j) r[j] = unpk(din[j]);
    fft16<-1, true>(r);
    float sn, cs;
    __sincosf(-6.283185307179586f * (float)t / 4096.f, &sn, &cs);
    cplx w = {cs, sn};
    TW_TREE(w);
    TW_APPLY(r);
    cplx* Zb = &Z[swt];
#pragma unroll
    for (int k1 = 0; k1 < 16; ++k1) Zb[k1 << 8] = r[POS(k1)];
  }
  __syncthreads();

  // ---- F2: DFT16 over m1 (stride 16), twiddle W256^{m2*j1} ----
  {
    const int g = t >> 4, m2 = t & 15;
    const int base = g << 8;
#pragma unroll
    for (int m1 = 0; m1 < 16; ++m1) r[m1] = Z[base + (m1 << 4) + (m2 ^ m1)];
    fft16<-1, false>(r);
    float sn, cs;
    __sincosf(-6.283185307179586f * (float)m2 / 256.f, &sn, &cs);
    cplx w = {cs, sn};
    TW_TREE(w);
    TW_APPLY(r);
#pragma unroll
    for (int j1 = 0; j1 < 16; ++j1) Z[base + (j1 << 4) + (m2 ^ j1)] = r[POS(j1)];
  }
  __syncthreads();

  // ---- F3 + pointwise-combine + I1, register-lean fusion ----
  {
    const int k1 = t >> 4, j1 = t & 15;
    const int base = (k1 << 8) + (j1 << 4);

    // F3: read own run (output of F2), DFT16 over m2, publish to LDS for partner
#pragma unroll
    for (int m2 = 0; m2 < 16; ++m2) r[m2] = Z[base + (m2 ^ j1)];
    fft16<-1, false>(r);
#pragma unroll
    for (int j2 = 0; j2 < 16; ++j2) Z[base + (j2 ^ j1)] = r[POS(j2)];
    __syncthreads();

    // pointwise combine: W[j2] = alpha*own[j2] + beta*conj(partner[15-j2])
    // partner run: (16-k1, 15-j1) for k1>0; (0, (16-j1)&15) for k1==0.
    // Thread 0 (run 0,0) is self-paired with element order (16-j2)&15 -> regs.
    const int j1p = (k1 == 0) ? ((16 - j1) & 15) : (15 - j1);
    const int base2 = ((k1 == 0) ? 0 : ((16 - k1) << 8)) + (j1p << 4);
    const float4* tb = tab + ((size_t)h << 12) + t;
    cplx Wv[16];
    if (t != 0) {
#pragma unroll
      for (int j2 = 0; j2 < 16; ++j2) {
        float4 cc = tb[j2 << 8];
        cplx zm = Z[base2 + ((15 - j2) ^ j1p)];
        cplx a_; a_.x = cc.x; a_.y = cc.y;
        cplx b_; b_.x = cc.z; b_.y = cc.w;
        cplx zmc; zmc.x = zm.x; zmc.y = -zm.y;
        Wv[j2] = pk_add(pk_cmul(a_, r[POS(j2)]), pk_cmul(b_, zmc));
      }
    } else {
#pragma unroll
      for (int j2 = 0; j2 < 16; ++j2) {
        float4 cc = tb[j2 << 8];
        cplx zm = r[POS((16 - j2) & 15)];
        cplx a_; a_.x = cc.x; a_.y = cc.y;
        cplx b_; b_.x = cc.z; b_.y = cc.w;
        cplx zmc; zmc.x = zm.x; zmc.y = -zm.y;
        Wv[j2] = pk_add(pk_cmul(a_, r[POS(j2)]), pk_cmul(b_, zmc));
      }
    }
    __syncthreads();  // all partner reads done before overwriting runs

    // I1: IDFT16 over j2, twiddle e^{+2pi i j1*m2/256}, write own run
    fft16<1, false>(Wv);
    float sn, cs;
    __sincosf(6.283185307179586f * (float)j1 / 256.f, &sn, &cs);
    cplx w = {cs, sn};
    TW_TREE(w);
    TW_APPLY(Wv);
#pragma unroll
    for (int m2 = 0; m2 < 16; ++m2) Z[base + (m2 ^ j1)] = Wv[POS(m2)];
  }
  __syncthreads();

  // ---- I2: IDFT16 over j1 (stride 16), twiddle e^{+2pi i k1*(m1*16+m2)/4096} ----
  {
    const int k1 = t >> 4, m2 = t & 15;
#pragma unroll
    for (int j1 = 0; j1 < 16; ++j1) r[j1] = Z[(k1 << 8) + (j1 << 4) + (m2 ^ j1)];
    fft16<1, false>(r);
    float sn, cs;
    __sincosf(6.283185307179586f * (float)(k1 * m2) / 4096.f, &sn, &cs);
    cplx b0 = {cs, sn};
    __sincosf(6.283185307179586f * (float)k1 / 256.f, &sn, &cs);
    cplx w = {cs, sn};
    TWS_TREE(b0, w);
    TWS_APPLY(r);
#pragma unroll
    for (int m1 = 0; m1 < 16; ++m1) Z[(k1 << 8) + (m1 << 4) + (m2 ^ m1)] = r[POS(m1)];
  }
  __syncthreads();

  // ---- I3: IDFT16 over k1 (stride 256), bf16x2 coalesced global store ----
  {
    cplx* Zb = &Z[swt];
#pragma unroll
    for (int k1 = 0; k1 < 16; ++k1) r[k1] = Zb[k1 << 8];
    fft16<1, false>(r);
#pragma unroll
    for (int n1 = 0; n1 < 8; ++n1) {
      cplx v = r[POS(n1)];
      zrow[(n1 << 8) + t] = pkbf(v.x, v.y);
    }
  }
}

// ---------- pass 3: transpose back z (B,C,L/2) -> out (B,L,C) + mix ----------
__global__ __launch_bounds__(256) void mix_out(const unsigned* __restrict__ zin,
                                               const float* __restrict__ x,
                                               const float* __restrict__ mix_logit,
                                               float* __restrict__ outp) {
  __shared__ float T[64][33];
  const int b = blockIdx.z;
  const int l0 = blockIdx.x * 64;
  const int c0 = blockIdx.y * 32;
  const int h = c0 >> 6;
  const float ml = mix_logit[h];
  const float mix = 1.0f / (1.0f + __expf(-ml));
  const float omix = 1.0f - mix;
  const unsigned* yb = zin + (size_t)b * kC * kN2;
  const float* xb = x + (size_t)b * kL * kC;
  float* ob = outp + (size_t)b * kL * kC;
  const int tx = threadIdx.x & 31, ty = threadIdx.x >> 5;
  const int n0 = l0 >> 1;
#pragma unroll
  for (int i = 0; i < 32; i += 8) {
    int c = ty + i;
    unsigned d = yb[(size_t)(c0 + c) * kN2 + n0 + tx];
    T[2 * tx][c] = __uint_as_float(d << 16);
    T[2 * tx + 1][c] = __uint_as_float(d & 0xffff0000u);
  }
  __syncthreads();
#pragma unroll
  for (int i = 0; i < 64; i += 8) {
    int l = ty + i;
    size_t idx = (size_t)(l0 + l) * kC + c0 + tx;
    ob[idx] = mix * T[l][tx] + omix * xb[idx];
  }
}

// ---------- fallback (round-1 single kernel) if ws is too small ----------
__global__ __launch_bounds__(NTH) void fftconv_fallback(
    const float* __restrict__ x, const float* __restrict__ log_amp,
    const float* __restrict__ log_decay, const float* __restrict__ mix_logit,
    float* __restrict__ out) {
  __shared__ float2 Z[kZPad];
  const int row = blockIdx.x;
  const int d = row & (kD - 1);
  const int h = (row >> 6) & (kH - 1);
  const int b = row >> 10;
  const int t = threadIdx.x;
  const size_t rowoff = (size_t)b * kL * kC + (size_t)h * kD + (size_t)d;
  const float* xrow = x + rowoff;
  float* orow = out + rowoff;

  const float av = log_amp[h];
  const float dv = log_decay[h];
  const float amp = (av > 20.f) ? av : log1pf(__expf(av));
  const float dec = ((dv > 20.f) ? dv : log1pf(__expf(dv))) + 1e-4f;
  const float ampS = amp * (1.0f / (float)kM);
  const float ml = mix_logit[h];
  const float mix = 1.0f / (1.0f + __expf(-ml));
  const float omix = 1.0f - mix;

  for (int i = 0; i < kM / NTH; ++i) {
    int n = t + i * NTH;
    float2 z;
    if (n < kL / 2) {
      z.x = xrow[(size_t)(2 * n) * kC];
      z.y = xrow[(size_t)(2 * n + 1) * kC];
    } else {
      z = make_float2(0.f, 0.f);
    }
    Z[IDX(n)] = z;
  }
  __syncthreads();

  for (int Ls = kM; Ls >= 4; Ls >>= 2) {
    const int q = Ls >> 2;
    const float wstep = -6.283185307179586f / (float)Ls;
    for (int i = 0; i < kM / 4 / NTH; ++i) {
      int bt = t + i * NTH;
      int jj = bt & (q - 1);
      int base = ((bt - jj) << 2) + jj;
      float2 a = Z[IDX(base)], bb = Z[IDX(base + q)];
      float2 c = Z[IDX(base + 2 * q)], dd = Z[IDX(base + 3 * q)];
      float2 t0 = cadd(a, c), t1 = csub(a, c), t2 = cadd(bb, dd), t3 = csub(bb, dd);
      float2 u0 = cadd(t0, t2), u2 = csub(t0, t2);
      float2 it3 = cmuli(t3);
      float2 u1 = csub(t1, it3), u3 = cadd(t1, it3);
      float sn, cs;
      __sincosf(wstep * (float)jj, &sn, &cs);
      float2 w1 = make_float2(cs, sn);
      float2 w2 = cmul(w1, w1);
      float2 w3 = cmul(w2, w1);
      Z[IDX(base)] = u0;
      Z[IDX(base + q)] = cmul(u1, w1);
      Z[IDX(base + 2 * q)] = cmul(u2, w2);
      Z[IDX(base + 3 * q)] = cmul(u3, w3);
    }
    __syncthreads();
  }

  for (int i = 0; i <= kM / 2 / NTH; ++i) {
    int k = t + i * NTH;
    if (k > kM / 2) continue;
    if (k == 0) {
      float2 Z0 = Z[IDX(0)];
      float X0 = Z0.x + Z0.y;
      float XM = Z0.x - Z0.y;
      float2 f0 = filt_val(0.f, ampS, dec);
      float2 fM = filt_val((float)kM, ampS, dec);
      float Y0 = X0 * f0.x;
      float YM = XM * fM.x;
      Z[IDX(0)] = make_float2(0.5f * (Y0 + YM), 0.5f * (Y0 - YM));
    } else if (k == kM / 2) {
      unsigned p = dr4(kM / 2);
      float2 Zk = Z[IDX(p)];
      float2 f = filt_val((float)(kM / 2), ampS, dec);
      float2 Y = cmul(cconj(Zk), f);
      Z[IDX(p)] = cconj(Y);
    } else {
      unsigned pk = dr4((unsigned)k), pmk = dr4((unsigned)(kM - k));
      float2 Zk = Z[IDX(pk)], Zmk = Z[IDX(pmk)];
      float2 A = cscale(cadd(Zk, cconj(Zmk)), 0.5f);
      float2 Bv = cscale(csub(Zk, cconj(Zmk)), 0.5f);
      float sn, cs;
      __sincosf(-3.14159265358979323846f * (float)k / (float)kM, &sn, &cs);
      float2 tw = make_float2(cs, sn);
      float2 P = cmuli(cmul(tw, Bv));
      float2 Xk = csub(A, P);
      float2 Xmk = cconj(cadd(A, P));
      float2 Yk = cmul(Xk, filt_val((float)k, ampS, dec));
      float2 Ymk = cmul(Xmk, filt_val((float)(kM - k), ampS, dec));
      float2 Ev = cscale(cadd(Yk, cconj(Ymk)), 0.5f);
      float2 Ov = cscale(cmul(cconj(tw), csub(Yk, cconj(Ymk))), 0.5f);
      float2 iO = cmuli(Ov);
      Z[IDX(pk)] = cadd(Ev, iO);
      Z[IDX(pmk)] = cconj(csub(Ev, iO));
    }
  }
  __syncthreads();

  for (int Ls = 4; Ls <= kM; Ls <<= 2) {
    const int q = Ls >> 2;
    const float wstep = 6.283185307179586f / (float)Ls;
    for (int i = 0; i < kM / 4 / NTH; ++i) {
      int bt = t + i * NTH;
      int jj = bt & (q - 1);
      int base = ((bt - jj) << 2) + jj;
      float sn, cs;
      __sincosf(wstep * (float)jj, &sn, &cs);
      float2 w1 = make_float2(cs, sn);
      float2 w2 = cmul(w1, w1);
      float2 w3 = cmul(w2, w1);
      float2 a = Z[IDX(base)];
      float2 bb = cmul(Z[IDX(base + q)], w1);
      float2 c = cmul(Z[IDX(base + 2 * q)], w2);
      float2 dd = cmul(Z[IDX(base + 3 * q)], w3);
      float2 s0 = cadd(a, c), s1 = csub(a, c), s2 = cadd(bb, dd), s3 = csub(bb, dd);
      float2 is3 = cmuli(s3);
      Z[IDX(base)] = cadd(s0, s2);
      Z[IDX(base + 2 * q)] = csub(s0, s2);
      Z[IDX(base + q)] = cadd(s1, is3);
      Z[IDX(base + 3 * q)] = csub(s1, is3);
    }
    __syncthreads();
  }

  for (int i = 0; i < kL / 2 / NTH; ++i) {
    int n = t + i * NTH;
    float2 w = Z[IDX(n)];
    size_t i0 = (size_t)(2 * n) * kC;
    float x0 = xrow[i0];
    float x1 = xrow[i0 + kC];
    orow[i0] = mix * w.x + omix * x0;
    orow[i0 + kC] = mix * w.y + omix * x1;
  }
}

extern "C" void kernel_launch(void* const* d_in, const int* in_sizes, int n_in,
                              void* d_out, int out_size, void* d_ws, size_t ws_size,
                              hipStream_t stream) {
  const float* x = (const float*)d_in[0];
  const float* la = (const float*)d_in[1];
  const float* ld = (const float*)d_in[2];
  const float* ml = (const float*)d_in[3];
  float* out = (float*)d_out;
  const size_t zbytes = (size_t)kB * kC * kN2 * sizeof(unsigned);        // 32 MiB
  const size_t tabbytes = (size_t)kH * 16 * 256 * sizeof(float4);        // 1 MiB
  if (ws_size >= zbytes + tabbytes) {
    unsigned* wsz = (unsigned*)d_ws;
    float4* tab = (float4*)((char*)d_ws + zbytes);
    build_table<<<dim3(16, kH), dim3(256), 0, stream>>>(la, ld, tab);
    transpose_fwd<<<dim3(kL / 64, kC / 32, kB), dim3(256), 0, stream>>>(x, wsz);
    fft_rows<<<dim3(kB * kC), dim3(NTH), 0, stream>>>(wsz, tab);
    mix_out<<<dim3(kL / 64, kC / 32, kB), dim3(256), 0, stream>>>(wsz, x, ml, out);
  } else {
    fftconv_fallback<<<dim3(kB * kC), dim3(NTH), 0, stream>>>(x, la, ld, ml, out);
  }
}

// Round 11
// 95.817 us; speedup vs baseline: 1.4186x; 1.0244x over previous
//
#include <hip/hip_runtime.h>
#include <math.h>

namespace {
constexpr int kB = 4;
constexpr int kL = 4096;
constexpr int kH = 16;
constexpr int kD = 64;
constexpr int kC = kH * kD;       // 1024 channels
constexpr int kM = 4096;          // complex FFT length (rfft of 8192 via packing)
constexpr int kN2 = kL / 2;       // 2048 packed complex samples per row
constexpr int NTH = 256;
constexpr int kTabIters = 9;      // pointwise iterations 0..8

// ---------------- scalar complex helpers (aux kernels) ----------------
__device__ __forceinline__ float2 cmul(float2 a, float2 b) {
  return make_float2(a.x * b.x - a.y * b.y, a.x * b.y + a.y * b.x);
}
__device__ __forceinline__ float2 cadd(float2 a, float2 b) { return make_float2(a.x + b.x, a.y + b.y); }
__device__ __forceinline__ float2 csub(float2 a, float2 b) { return make_float2(a.x - b.x, a.y - b.y); }
__device__ __forceinline__ float2 cconj(float2 a) { return make_float2(a.x, -a.y); }
__device__ __forceinline__ float2 cmuli(float2 a) { return make_float2(-a.y, a.x); }  // i*a
__device__ __forceinline__ float2 cscale(float2 a, float s) { return make_float2(a.x * s, a.y * s); }

// ---------------- packed-FP32 complex helpers (fft_rows) ----------------
typedef float cplx __attribute__((ext_vector_type(2)));

__device__ __forceinline__ cplx pk_add(cplx a, cplx b) {
  cplx r;
  asm("v_pk_add_f32 %0, %1, %2" : "=v"(r) : "v"(a), "v"(b));
  return r;
}
__device__ __forceinline__ cplx pk_sub(cplx a, cplx b) {
  cplx r;
  asm("v_pk_add_f32 %0, %1, %2 neg_lo:[0,1] neg_hi:[0,1]" : "=v"(r) : "v"(a), "v"(b));
  return r;
}
// a + i*b = (a.x - b.y, a.y + b.x)
__device__ __forceinline__ cplx pk_addpi(cplx a, cplx b) {
  cplx r;
  asm("v_pk_add_f32 %0, %1, %2 op_sel:[0,1] op_sel_hi:[1,0] neg_lo:[0,1]" : "=v"(r) : "v"(a), "v"(b));
  return r;
}
// a - i*b = (a.x + b.y, a.y - b.x)
__device__ __forceinline__ cplx pk_addmi(cplx a, cplx b) {
  cplx r;
  asm("v_pk_add_f32 %0, %1, %2 op_sel:[0,1] op_sel_hi:[1,0] neg_hi:[0,1]" : "=v"(r) : "v"(a), "v"(b));
  return r;
}
// complex multiply: 2 VOP3P ops
__device__ __forceinline__ cplx pk_cmul(cplx a, cplx b) {
  cplx t, r;
  asm("v_pk_mul_f32 %0, %1, %2 op_sel:[0,0] op_sel_hi:[0,1]" : "=v"(t) : "v"(a), "v"(b));
  asm("v_pk_fma_f32 %0, %1, %2, %3 op_sel:[1,1,0] op_sel_hi:[1,0,1] neg_lo:[0,1,0]"
      : "=v"(r) : "v"(a), "v"(b), "v"(t));
  return r;
}
// complex multiply by conjugate: r = a * conj(b)
// t = (ax*bx, -ax*by); r = (ay*by + t.lo, ay*bx + t.hi) = (ax*bx+ay*by, ay*bx-ax*by)
__device__ __forceinline__ cplx pk_cmulc(cplx a, cplx b) {
  cplx t, r;
  asm("v_pk_mul_f32 %0, %1, %2 op_sel:[0,0] op_sel_hi:[0,1] neg_hi:[0,1]" : "=v"(t) : "v"(a), "v"(b));
  asm("v_pk_fma_f32 %0, %1, %2, %3 op_sel:[1,1,0] op_sel_hi:[1,0,1]"
      : "=v"(r) : "v"(a), "v"(b), "v"(t));
  return r;
}

// bf16x2 pack (RNE) / unpack
__device__ __forceinline__ unsigned pkbf(float lo, float hi) {
  unsigned r;
  asm("v_cvt_pk_bf16_f32 %0, %1, %2" : "=v"(r) : "v"(lo), "v"(hi));
  return r;
}
__device__ __forceinline__ cplx unpk(unsigned d) {
  cplx r;
  r.x = __uint_as_float(d << 16);
  r.y = __uint_as_float(d & 0xffff0000u);
  return r;
}

// base-4 digit reversal of a 12-bit index (fallback kernel only)
__device__ __forceinline__ unsigned dr4(unsigned p) {
  unsigned r = __brev(p) >> 20;
  return ((r & 0x555u) << 1) | ((r >> 1) & 0x555u);
}
// base-16 digit reversal of a 12-bit index (involution)
__device__ __forceinline__ unsigned dr16(unsigned p) {
  return ((p & 15u) << 8) | (p & 0xF0u) | (p >> 8);
}
// XOR LDS swizzle (cplx index space): phys = p ^ ((p>>4)&15)
__device__ __forceinline__ int SW(int i) { return i ^ ((i >> 4) & 15); }
// after in-register DFT16, X[k] lives at register slot POS(k)
#define POS(k) ((((k) & 3) << 2) | ((k) >> 2))

// fallback-kernel padding
__device__ __forceinline__ int IDX(int i) { return i + (i >> 4); }
constexpr int kZPad = kM + (kM >> 4);

// depth-4 twiddle power tree: W1..W15 = w^1..w^15
#define TW_TREE(w)                                                            \
  cplx W1 = (w), W2 = pk_cmul(W1, W1), W4 = pk_cmul(W2, W2),                  \
       W8 = pk_cmul(W4, W4);                                                  \
  cplx W3 = pk_cmul(W2, W1), W5 = pk_cmul(W4, W1), W6 = pk_cmul(W4, W2),      \
       W7 = pk_cmul(W4, W3);                                                  \
  cplx W9 = pk_cmul(W8, W1), W10 = pk_cmul(W8, W2), W11 = pk_cmul(W8, W3),    \
       W12 = pk_cmul(W8, W4);                                                 \
  cplx W13 = pk_cmul(W8, W5), W14 = pk_cmul(W8, W6), W15 = pk_cmul(W8, W7);

#define TW_APPLY(r)                                                           \
  r[POS(1)] = pk_cmul(r[POS(1)], W1);   r[POS(2)] = pk_cmul(r[POS(2)], W2);   \
  r[POS(3)] = pk_cmul(r[POS(3)], W3);   r[POS(4)] = pk_cmul(r[POS(4)], W4);   \
  r[POS(5)] = pk_cmul(r[POS(5)], W5);   r[POS(6)] = pk_cmul(r[POS(6)], W6);   \
  r[POS(7)] = pk_cmul(r[POS(7)], W7);   r[POS(8)] = pk_cmul(r[POS(8)], W8);   \
  r[POS(9)] = pk_cmul(r[POS(9)], W9);   r[POS(10)] = pk_cmul(r[POS(10)], W10);\
  r[POS(11)] = pk_cmul(r[POS(11)], W11); r[POS(12)] = pk_cmul(r[POS(12)], W12);\
  r[POS(13)] = pk_cmul(r[POS(13)], W13); r[POS(14)] = pk_cmul(r[POS(14)], W14);\
  r[POS(15)] = pk_cmul(r[POS(15)], W15);

// shifted tree: B[k] = b0 * w^k, k = 0..15, depth ~4
#define TWS_TREE(b0, w)                                                       \
  cplx P2 = pk_cmul(w, w), P4 = pk_cmul(P2, P2), P8 = pk_cmul(P4, P4);        \
  cplx B0 = (b0), B1 = pk_cmul(b0, w), B2 = pk_cmul(B0, P2),                  \
       B3 = pk_cmul(B1, P2);                                                  \
  cplx B4 = pk_cmul(B0, P4), B5 = pk_cmul(B1, P4), B6 = pk_cmul(B2, P4),      \
       B7 = pk_cmul(B3, P4);                                                  \
  cplx B8 = pk_cmul(B0, P8), B9 = pk_cmul(B1, P8), B10 = pk_cmul(B2, P8),     \
       B11 = pk_cmul(B3, P8);                                                 \
  cplx B12 = pk_cmul(B4, P8), B13 = pk_cmul(B5, P8), B14 = pk_cmul(B6, P8),   \
       B15 = pk_cmul(B7, P8);

#define TWS_APPLY(r)                                                          \
  r[POS(0)] = pk_cmul(r[POS(0)], B0);   r[POS(1)] = pk_cmul(r[POS(1)], B1);   \
  r[POS(2)] = pk_cmul(r[POS(2)], B2);   r[POS(3)] = pk_cmul(r[POS(3)], B3);   \
  r[POS(4)] = pk_cmul(r[POS(4)], B4);   r[POS(5)] = pk_cmul(r[POS(5)], B5);   \
  r[POS(6)] = pk_cmul(r[POS(6)], B6);   r[POS(7)] = pk_cmul(r[POS(7)], B7);   \
  r[POS(8)] = pk_cmul(r[POS(8)], B8);   r[POS(9)] = pk_cmul(r[POS(9)], B9);   \
  r[POS(10)] = pk_cmul(r[POS(10)], B10); r[POS(11)] = pk_cmul(r[POS(11)], B11);\
  r[POS(12)] = pk_cmul(r[POS(12)], B12); r[POS(13)] = pk_cmul(r[POS(13)], B13);\
  r[POS(14)] = pk_cmul(r[POS(14)], B14); r[POS(15)] = pk_cmul(r[POS(15)], B15);

// filt[k] = amp * (1 + i k)^(-dec), with 1/M ifft scale folded into ampS
__device__ __forceinline__ float2 filt_val(float k, float ampS, float dec) {
  float mag = ampS * __expf(-0.5f * dec * log1pf(k * k));
  float ph = -dec * atanf(k);
  float s, c;
  __sincosf(ph, &s, &c);
  return make_float2(mag * c, mag * s);
}

// ---- fully-unrolled 16-point DFT in registers (packed-FP32) ----
template <int S, bool HZ>
__device__ __forceinline__ void fft16(cplx r[16]) {
  constexpr float C1 = 0.92387953251128674f;
  constexpr float S1 = 0.38268343236508978f;
  constexpr float R2 = 0.70710678118654752f;
  const float sg = (float)S;
  const cplx Wa = {C1, sg * S1};
  const cplx Wb = {R2, sg * R2};
  const cplx Wc = {S1, sg * C1};
  const cplx Wd = {-R2, sg * R2};
  const cplx We = {-C1, -sg * S1};
#pragma unroll
  for (int n2 = 0; n2 < 4; ++n2) {
    cplx t0, t1, t2, t3;
    if (HZ) {
      t0 = r[n2]; t1 = r[n2]; t2 = r[n2 + 4]; t3 = r[n2 + 4];
    } else {
      cplx a0 = r[n2], a1 = r[n2 + 4], a2 = r[n2 + 8], a3 = r[n2 + 12];
      t0 = pk_add(a0, a2); t1 = pk_sub(a0, a2); t2 = pk_add(a1, a3); t3 = pk_sub(a1, a3);
    }
    cplx u0 = pk_add(t0, t2);
    cplx u2 = pk_sub(t0, t2);
    cplx u1 = (S < 0) ? pk_addmi(t1, t3) : pk_addpi(t1, t3);
    cplx u3 = (S < 0) ? pk_addpi(t1, t3) : pk_addmi(t1, t3);
    if (n2 == 0) { r[0] = u0; r[4] = u1; r[8] = u2; r[12] = u3; }
    if (n2 == 1) { r[1] = u0; r[5] = pk_cmul(u1, Wa); r[9] = pk_cmul(u2, Wb); r[13] = pk_cmul(u3, Wc); }
    if (n2 == 2) {
      r[2] = u0; r[6] = pk_cmul(u1, Wb);
      cplx m;
      if (S < 0) { m.x = u2.y; m.y = -u2.x; } else { m.x = -u2.y; m.y = u2.x; }
      r[10] = m;
      r[14] = pk_cmul(u3, Wd);
    }
    if (n2 == 3) { r[3] = u0; r[7] = pk_cmul(u1, Wc); r[11] = pk_cmul(u2, Wd); r[15] = pk_cmul(u3, We); }
  }
#pragma unroll
  for (int s = 0; s < 4; ++s) {
    cplx b0 = r[4 * s], b1 = r[4 * s + 1], b2 = r[4 * s + 2], b3 = r[4 * s + 3];
    cplx t0 = pk_add(b0, b2), t1 = pk_sub(b0, b2), t2 = pk_add(b1, b3), t3 = pk_sub(b1, b3);
    r[4 * s] = pk_add(t0, t2);
    r[4 * s + 2] = pk_sub(t0, t2);
    r[4 * s + 1] = (S < 0) ? pk_addmi(t1, t3) : pk_addpi(t1, t3);
    r[4 * s + 3] = (S < 0) ? pk_addpi(t1, t3) : pk_addmi(t1, t3);
  }
}

// pointwise pair map (verified algebra), used only by table building
__device__ __forceinline__ void pw_pair(float2 Zk, float2 Zmk, int k, float ampS, float dec,
                                        float2* Wk, float2* Wmk) {
  float2 A = cscale(cadd(Zk, cconj(Zmk)), 0.5f);
  float2 Bv = cscale(csub(Zk, cconj(Zmk)), 0.5f);
  float sn, cs;
  __sincosf(-3.14159265358979323846f * (float)k / (float)kM, &sn, &cs);
  float2 tw = make_float2(cs, sn);
  float2 P = cmuli(cmul(tw, Bv));
  float2 Xk = csub(A, P);
  float2 Xmk = cconj(cadd(A, P));
  float2 Yk = cmul(Xk, filt_val((float)k, ampS, dec));
  float2 Ymk = cmul(Xmk, filt_val((float)(kM - k), ampS, dec));
  float2 Ev = cscale(cadd(Yk, cconj(Ymk)), 0.5f);
  float2 Ov = cscale(cmul(cconj(tw), csub(Yk, cconj(Ymk))), 0.5f);
  float2 iO = cmuli(Ov);
  *Wk = cadd(Ev, iO);
  *Wmk = cconj(csub(Ev, iO));
}
}  // namespace

// ---------- pass 1 (merged): transpose+pack x -> z bf16x2, AND build coef table ----------
// blockIdx.z < kB : transpose slab; blockIdx.z == kB : table blocks (x<9, y<16)
__global__ __launch_bounds__(256) void transpose_fwd(const float* __restrict__ in,
                                                     unsigned* __restrict__ zout,
                                                     const float* __restrict__ la,
                                                     const float* __restrict__ ld,
                                                     float2* __restrict__ tab) {
  __shared__ float T[64][33];
  if (blockIdx.z == kB) {
    const int i = blockIdx.x;   // 0..8
    const int h = blockIdx.y;
    if (i >= kTabIters || h >= kH) return;
    const int t = threadIdx.x;  // 0..255
    float av = la[h], dv = ld[h];
    float amp = (av > 20.f) ? av : log1pf(__expf(av));
    float dec = ((dv > 20.f) ? dv : log1pf(__expf(dv))) + 1e-4f;
    float ampS = amp * (1.0f / (float)kM);
    float2 e0 = make_float2(0.f, 0.f), e1 = e0, e2 = e0, e3 = e0;
    const int c = t & 15;
    if (i == 0 && t == 0) {
      float F0 = filt_val(0.f, ampS, dec).x;
      float FM = filt_val((float)kM, ampS, dec).x;
      e0 = make_float2(0.5f * (F0 + FM), 0.5f * (F0 - FM));
      e1 = make_float2(0.5f * (F0 - FM), 0.5f * (F0 + FM));
    } else if (i == 0 && t == 8) {
      e0 = cconj(filt_val((float)(kM / 2), ampS, dec));  // bin 2048 single coeff
    } else if ((i >= 1 && i <= 7) || c < 8) {
      int p = (i << 8) + t;
      int k = (int)dr16((unsigned)p);
      float2 a, b, g, d;
      pw_pair(make_float2(1.f, 0.f), make_float2(0.f, 0.f), k, ampS, dec, &a, &g);
      pw_pair(make_float2(0.f, 0.f), make_float2(1.f, 0.f), k, ampS, dec, &b, &d);
      e0 = a; e1 = b; e2 = g; e3 = d;
    }
    float2* e = tab + ((size_t)(h * kTabIters + i) * 256 + t) * 4;
    e[0] = e0; e[1] = e1; e[2] = e2; e[3] = e3;
    return;
  }
  const int b = blockIdx.z;
  const int l0 = blockIdx.x * 64;
  const int c0 = blockIdx.y * 32;
  const float* ib = in + (size_t)b * kL * kC;
  unsigned* ob = zout + (size_t)b * kC * kN2;
  const int tx = threadIdx.x & 31, ty = threadIdx.x >> 5;
#pragma unroll
  for (int i = 0; i < 64; i += 8)
    T[ty + i][tx] = ib[(size_t)(l0 + ty + i) * kC + c0 + tx];
  __syncthreads();
  const int n0 = l0 >> 1;
#pragma unroll
  for (int i = 0; i < 32; i += 8) {
    int c = ty + i;
    ob[(size_t)(c0 + c) * kN2 + n0 + tx] = pkbf(T[2 * tx][c], T[2 * tx + 1][c]);
  }
}

// ---------- pass 2: per-row FFT conv (16^3 register radix-16, packed math) ----------
__global__ __launch_bounds__(NTH) void fft_rows(unsigned* __restrict__ zio,
                                                const float2* __restrict__ tab) {
  __shared__ cplx Z[kM];  // 32 KB
  const int row = blockIdx.x;  // b*1024 + c
  const int h = (row >> 6) & (kH - 1);
  const int t = threadIdx.x;
  unsigned* zrow = zio + (size_t)row * kN2;

  cplx r[16];
  const int swt = t ^ ((t >> 4) & 15);
  // H tree: powers of e^{-2pi i (t&15)/256}; built in F2, reused (conjugated) in I1
  cplx H1, H2, H3, H4, H5, H6, H7, H8, H9, H10, H11, H12, H13, H14, H15;

  // ---- F1: global load (bf16x2), DFT16 over n1, twiddle W4096^{t*k1} ----
  {
    unsigned din[8];
#pragma unroll
    for (int j = 0; j < 8; ++j) din[j] = zrow[t + (j << 8)];
#pragma unroll
    for (int j = 0; j < 8; ++j) r[j] = unpk(din[j]);
    fft16<-1, true>(r);
    float sn, cs;
    __sincosf(-6.283185307179586f * (float)t / 4096.f, &sn, &cs);
    cplx w = {cs, sn};
    TW_TREE(w);
    TW_APPLY(r);
    cplx* Zb = &Z[swt];
#pragma unroll
    for (int k1 = 0; k1 < 16; ++k1) Zb[k1 << 8] = r[POS(k1)];
  }
  __syncthreads();

  // ---- F2: DFT16 over m1 (stride 16), twiddle W256^{m2*j1}; tree kept for I1 ----
  {
    const int g = t >> 4, m2 = t & 15;
    const int base = g << 8;
#pragma unroll
    for (int m1 = 0; m1 < 16; ++m1) r[m1] = Z[base + (m1 << 4) + (m2 ^ m1)];
    fft16<-1, false>(r);
    float sn, cs;
    __sincosf(-6.283185307179586f * (float)m2 / 256.f, &sn, &cs);
    cplx w = {cs, sn};
    H1 = w; H2 = pk_cmul(H1, H1); H4 = pk_cmul(H2, H2); H8 = pk_cmul(H4, H4);
    H3 = pk_cmul(H2, H1); H5 = pk_cmul(H4, H1); H6 = pk_cmul(H4, H2); H7 = pk_cmul(H4, H3);
    H9 = pk_cmul(H8, H1); H10 = pk_cmul(H8, H2); H11 = pk_cmul(H8, H3); H12 = pk_cmul(H8, H4);
    H13 = pk_cmul(H8, H5); H14 = pk_cmul(H8, H6); H15 = pk_cmul(H8, H7);
    r[POS(1)] = pk_cmul(r[POS(1)], H1);   r[POS(2)] = pk_cmul(r[POS(2)], H2);
    r[POS(3)] = pk_cmul(r[POS(3)], H3);   r[POS(4)] = pk_cmul(r[POS(4)], H4);
    r[POS(5)] = pk_cmul(r[POS(5)], H5);   r[POS(6)] = pk_cmul(r[POS(6)], H6);
    r[POS(7)] = pk_cmul(r[POS(7)], H7);   r[POS(8)] = pk_cmul(r[POS(8)], H8);
    r[POS(9)] = pk_cmul(r[POS(9)], H9);   r[POS(10)] = pk_cmul(r[POS(10)], H10);
    r[POS(11)] = pk_cmul(r[POS(11)], H11); r[POS(12)] = pk_cmul(r[POS(12)], H12);
    r[POS(13)] = pk_cmul(r[POS(13)], H13); r[POS(14)] = pk_cmul(r[POS(14)], H14);
    r[POS(15)] = pk_cmul(r[POS(15)], H15);
#pragma unroll
    for (int j1 = 0; j1 < 16; ++j1) Z[base + (j1 << 4) + (m2 ^ j1)] = r[POS(j1)];
  }
  __syncthreads();

  // ---- F3: DFT16 over m2 (contiguous permuted 16), no twiddle ----
  {
    const int g = t >> 4, j1 = t & 15;
    const int base = (g << 8) + (j1 << 4);
#pragma unroll
    for (int m2 = 0; m2 < 16; ++m2) r[m2] = Z[base + (m2 ^ j1)];
    fft16<-1, false>(r);
#pragma unroll
    for (int j2 = 0; j2 < 16; ++j2) Z[base + (j2 ^ j1)] = r[POS(j2)];
  }
  __syncthreads();

  // ---- pointwise: position-indexed pairs, conflict-free & coalesced table ----
  {
    const int c = t & 15;
    const float4* tpz = (const float4*)(tab + (size_t)h * kTabIters * 256 * 4);
#pragma unroll
    for (int i = 0; i <= 8; ++i) {
      const float4* tp = tpz + ((i << 8) + t) * 2;
      float4 q0 = tp[0], q1 = tp[1];
      if (i == 0 && t == 0) {
        cplx Z0 = Z[0];
        cplx o; o.x = q0.x * Z0.x + q0.y * Z0.y; o.y = q0.z * Z0.x + q0.w * Z0.y;
        Z[0] = o;
      } else if (i == 0 && t == 8) {
        cplx f; f.x = q0.x; f.y = q0.y;
        Z[8] = pk_cmul(f, Z[8]);  // SW(8)=8, bin 2048
      } else if ((i >= 1 && i <= 7) || c < 8) {
        int p = (i << 8) + t;
        int p2 = (i == 0) ? ((t < 16) ? (16 - t) : (271 - t))
                          : (((16 - i) << 8) + (255 - t));
        int sp = SW(p), sp2 = SW(p2);
        cplx Zk = Z[sp], Zmk = Z[sp2];
        cplx e0 = {q0.x, q0.y}, e1 = {q0.z, q0.w};
        cplx e2 = {q1.x, q1.y}, e3 = {q1.z, q1.w};
        cplx cZk = {Zk.x, -Zk.y}, cZmk = {Zmk.x, -Zmk.y};
        Z[sp] = pk_add(pk_cmul(e0, Zk), pk_cmul(e1, cZmk));
        Z[sp2] = pk_add(pk_cmul(e2, cZk), pk_cmul(e3, Zmk));
      }
    }
  }
  __syncthreads();

  // ---- I1: IDFT16 over j2; twiddle = conj(H) (e^{+2pi i j1*m2/256}) ----
  {
    const int k1 = t >> 4, j1 = t & 15;
    const int base = (k1 << 8) + (j1 << 4);
#pragma unroll
    for (int j2 = 0; j2 < 16; ++j2) r[j2] = Z[base + (j2 ^ j1)];
    fft16<1, false>(r);
    r[POS(1)] = pk_cmulc(r[POS(1)], H1);   r[POS(2)] = pk_cmulc(r[POS(2)], H2);
    r[POS(3)] = pk_cmulc(r[POS(3)], H3);   r[POS(4)] = pk_cmulc(r[POS(4)], H4);
    r[POS(5)] = pk_cmulc(r[POS(5)], H5);   r[POS(6)] = pk_cmulc(r[POS(6)], H6);
    r[POS(7)] = pk_cmulc(r[POS(7)], H7);   r[POS(8)] = pk_cmulc(r[POS(8)], H8);
    r[POS(9)] = pk_cmulc(r[POS(9)], H9);   r[POS(10)] = pk_cmulc(r[POS(10)], H10);
    r[POS(11)] = pk_cmulc(r[POS(11)], H11); r[POS(12)] = pk_cmulc(r[POS(12)], H12);
    r[POS(13)] = pk_cmulc(r[POS(13)], H13); r[POS(14)] = pk_cmulc(r[POS(14)], H14);
    r[POS(15)] = pk_cmulc(r[POS(15)], H15);
#pragma unroll
    for (int m2 = 0; m2 < 16; ++m2) Z[base + (m2 ^ j1)] = r[POS(m2)];
  }
  __syncthreads();

  // ---- I2: IDFT16 over j1 (stride 16), twiddle e^{+2pi i k1*(m1*16+m2)/4096} ----
  {
    const int k1 = t >> 4, m2 = t & 15;
#pragma unroll
    for (int j1 = 0; j1 < 16; ++j1) r[j1] = Z[(k1 << 8) + (j1 << 4) + (m2 ^ j1)];
    fft16<1, false>(r);
    float sn, cs;
    __sincosf(6.283185307179586f * (float)(k1 * m2) / 4096.f, &sn, &cs);
    cplx b0 = {cs, sn};
    __sincosf(6.283185307179586f * (float)k1 / 256.f, &sn, &cs);
    cplx w = {cs, sn};
    TWS_TREE(b0, w);
    TWS_APPLY(r);
#pragma unroll
    for (int m1 = 0; m1 < 16; ++m1) Z[(k1 << 8) + (m1 << 4) + (m2 ^ m1)] = r[POS(m1)];
  }
  __syncthreads();

  // ---- I3: IDFT16 over k1 (stride 256), bf16x2 coalesced global store ----
  {
    cplx* Zb = &Z[swt];
#pragma unroll
    for (int k1 = 0; k1 < 16; ++k1) r[k1] = Zb[k1 << 8];
    fft16<1, false>(r);
#pragma unroll
    for (int n1 = 0; n1 < 8; ++n1) {
      cplx v = r[POS(n1)];
      zrow[(n1 << 8) + t] = pkbf(v.x, v.y);
    }
  }
}

// ---------- pass 3: transpose back z (B,C,L/2) -> out (B,L,C) + mix ----------
__global__ __launch_bounds__(256) void mix_out(const unsigned* __restrict__ zin,
                                               const float* __restrict__ x,
                                               const float* __restrict__ mix_logit,
                                               float* __restrict__ outp) {
  __shared__ float T[64][33];
  const int b = blockIdx.z;
  const int l0 = blockIdx.x * 64;
  const int c0 = blockIdx.y * 32;
  const int h = c0 >> 6;
  const float ml = mix_logit[h];
  const float mix = 1.0f / (1.0f + __expf(-ml));
  const float omix = 1.0f - mix;
  const unsigned* yb = zin + (size_t)b * kC * kN2;
  const float* xb = x + (size_t)b * kL * kC;
  float* ob = outp + (size_t)b * kL * kC;
  const int tx = threadIdx.x & 31, ty = threadIdx.x >> 5;
  const int n0 = l0 >> 1;
#pragma unroll
  for (int i = 0; i < 32; i += 8) {
    int c = ty + i;
    unsigned d = yb[(size_t)(c0 + c) * kN2 + n0 + tx];
    T[2 * tx][c] = __uint_as_float(d << 16);
    T[2 * tx + 1][c] = __uint_as_float(d & 0xffff0000u);
  }
  __syncthreads();
#pragma unroll
  for (int i = 0; i < 64; i += 8) {
    int l = ty + i;
    size_t idx = (size_t)(l0 + l) * kC + c0 + tx;
    ob[idx] = mix * T[l][tx] + omix * xb[idx];
  }
}

// ---------- fallback (round-1 single kernel) if ws is too small ----------
__global__ __launch_bounds__(NTH) void fftconv_fallback(
    const float* __restrict__ x, const float* __restrict__ log_amp,
    const float* __restrict__ log_decay, const float* __restrict__ mix_logit,
    float* __restrict__ out) {
  __shared__ float2 Z[kZPad];
  const int row = blockIdx.x;
  const int d = row & (kD - 1);
  const int h = (row >> 6) & (kH - 1);
  const int b = row >> 10;
  const int t = threadIdx.x;
  const size_t rowoff = (size_t)b * kL * kC + (size_t)h * kD + (size_t)d;
  const float* xrow = x + rowoff;
  float* orow = out + rowoff;

  const float av = log_amp[h];
  const float dv = log_decay[h];
  const float amp = (av > 20.f) ? av : log1pf(__expf(av));
  const float dec = ((dv > 20.f) ? dv : log1pf(__expf(dv))) + 1e-4f;
  const float ampS = amp * (1.0f / (float)kM);
  const float ml = mix_logit[h];
  const float mix = 1.0f / (1.0f + __expf(-ml));
  const float omix = 1.0f - mix;

  for (int i = 0; i < kM / NTH; ++i) {
    int n = t + i * NTH;
    float2 z;
    if (n < kL / 2) {
      z.x = xrow[(size_t)(2 * n) * kC];
      z.y = xrow[(size_t)(2 * n + 1) * kC];
    } else {
      z = make_float2(0.f, 0.f);
    }
    Z[IDX(n)] = z;
  }
  __syncthreads();

  for (int Ls = kM; Ls >= 4; Ls >>= 2) {
    const int q = Ls >> 2;
    const float wstep = -6.283185307179586f / (float)Ls;
    for (int i = 0; i < kM / 4 / NTH; ++i) {
      int bt = t + i * NTH;
      int jj = bt & (q - 1);
      int base = ((bt - jj) << 2) + jj;
      float2 a = Z[IDX(base)], bb = Z[IDX(base + q)];
      float2 c = Z[IDX(base + 2 * q)], dd = Z[IDX(base + 3 * q)];
      float2 t0 = cadd(a, c), t1 = csub(a, c), t2 = cadd(bb, dd), t3 = csub(bb, dd);
      float2 u0 = cadd(t0, t2), u2 = csub(t0, t2);
      float2 it3 = cmuli(t3);
      float2 u1 = csub(t1, it3), u3 = cadd(t1, it3);
      float sn, cs;
      __sincosf(wstep * (float)jj, &sn, &cs);
      float2 w1 = make_float2(cs, sn);
      float2 w2 = cmul(w1, w1);
      float2 w3 = cmul(w2, w1);
      Z[IDX(base)] = u0;
      Z[IDX(base + q)] = cmul(u1, w1);
      Z[IDX(base + 2 * q)] = cmul(u2, w2);
      Z[IDX(base + 3 * q)] = cmul(u3, w3);
    }
    __syncthreads();
  }

  for (int i = 0; i <= kM / 2 / NTH; ++i) {
    int k = t + i * NTH;
    if (k > kM / 2) continue;
    if (k == 0) {
      float2 Z0 = Z[IDX(0)];
      float X0 = Z0.x + Z0.y;
      float XM = Z0.x - Z0.y;
      float2 f0 = filt_val(0.f, ampS, dec);
      float2 fM = filt_val((float)kM, ampS, dec);
      float Y0 = X0 * f0.x;
      float YM = XM * fM.x;
      Z[IDX(0)] = make_float2(0.5f * (Y0 + YM), 0.5f * (Y0 - YM));
    } else if (k == kM / 2) {
      unsigned p = dr4(kM / 2);
      float2 Zk = Z[IDX(p)];
      float2 f = filt_val((float)(kM / 2), ampS, dec);
      float2 Y = cmul(cconj(Zk), f);
      Z[IDX(p)] = cconj(Y);
    } else {
      unsigned pk = dr4((unsigned)k), pmk = dr4((unsigned)(kM - k));
      float2 Zk = Z[IDX(pk)], Zmk = Z[IDX(pmk)];
      float2 A = cscale(cadd(Zk, cconj(Zmk)), 0.5f);
      float2 Bv = cscale(csub(Zk, cconj(Zmk)), 0.5f);
      float sn, cs;
      __sincosf(-3.14159265358979323846f * (float)k / (float)kM, &sn, &cs);
      float2 tw = make_float2(cs, sn);
      float2 P = cmuli(cmul(tw, Bv));
      float2 Xk = csub(A, P);
      float2 Xmk = cconj(cadd(A, P));
      float2 Yk = cmul(Xk, filt_val((float)k, ampS, dec));
      float2 Ymk = cmul(Xmk, filt_val((float)(kM - k), ampS, dec));
      float2 Ev = cscale(cadd(Yk, cconj(Ymk)), 0.5f);
      float2 Ov = cscale(cmul(cconj(tw), csub(Yk, cconj(Ymk))), 0.5f);
      float2 iO = cmuli(Ov);
      Z[IDX(pk)] = cadd(Ev, iO);
      Z[IDX(pmk)] = cconj(csub(Ev, iO));
    }
  }
  __syncthreads();

  for (int Ls = 4; Ls <= kM; Ls <<= 2) {
    const int q = Ls >> 2;
    const float wstep = 6.283185307179586f / (float)Ls;
    for (int i = 0; i < kM / 4 / NTH; ++i) {
      int bt = t + i * NTH;
      int jj = bt & (q - 1);
      int base = ((bt - jj) << 2) + jj;
      float sn, cs;
      __sincosf(wstep * (float)jj, &sn, &cs);
      float2 w1 = make_float2(cs, sn);
      float2 w2 = cmul(w1, w1);
      float2 w3 = cmul(w2, w1);
      float2 a = Z[IDX(base)];
      float2 bb = cmul(Z[IDX(base + q)], w1);
      float2 c = cmul(Z[IDX(base + 2 * q)], w2);
      float2 dd = cmul(Z[IDX(base + 3 * q)], w3);
      float2 s0 = cadd(a, c), s1 = csub(a, c), s2 = cadd(bb, dd), s3 = csub(bb, dd);
      float2 is3 = cmuli(s3);
      Z[IDX(base)] = cadd(s0, s2);
      Z[IDX(base + 2 * q)] = csub(s0, s2);
      Z[IDX(base + q)] = cadd(s1, is3);
      Z[IDX(base + 3 * q)] = csub(s1, is3);
    }
    __syncthreads();
  }

  for (int i = 0; i < kL / 2 / NTH; ++i) {
    int n = t + i * NTH;
    float2 w = Z[IDX(n)];
    size_t i0 = (size_t)(2 * n) * kC;
    float x0 = xrow[i0];
    float x1 = xrow[i0 + kC];
    orow[i0] = mix * w.x + omix * x0;
    orow[i0 + kC] = mix * w.y + omix * x1;
  }
}

extern "C" void kernel_launch(void* const* d_in, const int* in_sizes, int n_in,
                              void* d_out, int out_size, void* d_ws, size_t ws_size,
                              hipStream_t stream) {
  const float* x = (const float*)d_in[0];
  const float* la = (const float*)d_in[1];
  const float* ld = (const float*)d_in[2];
  const float* ml = (const float*)d_in[3];
  float* out = (float*)d_out;
  const size_t zbytes = (size_t)kB * kC * kN2 * sizeof(unsigned);               // 32 MiB
  const size_t tabbytes = (size_t)kH * kTabIters * 256 * 4 * sizeof(float2);    // ~1.1 MiB
  if (ws_size >= zbytes + tabbytes) {
    unsigned* wsz = (unsigned*)d_ws;
    float2* tab = (float2*)((char*)d_ws + zbytes);
    transpose_fwd<<<dim3(kL / 64, kC / 32, kB + 1), dim3(256), 0, stream>>>(x, wsz, la, ld, tab);
    fft_rows<<<dim3(kB * kC), dim3(NTH), 0, stream>>>(wsz, tab);
    mix_out<<<dim3(kL / 64, kC / 32, kB), dim3(256), 0, stream>>>(wsz, x, ml, out);
  } else {
    fftconv_fallback<<<dim3(kB * kC), dim3(NTH), 0, stream>>>(x, la, ld, ml, out);
  }
}